// Round 6
// baseline (2713.067 us; speedup 1.0000x reference)
//
#include <hip/hip_runtime.h>

typedef __bf16  bf16x8 __attribute__((ext_vector_type(8)));
typedef float   f32x4  __attribute__((ext_vector_type(4)));
typedef float   f32x16 __attribute__((ext_vector_type(16)));

__device__ __constant__ int EDGE_A[19] = {1,8,9,1,11,12,1,2,3,2,1,5,6,5,0,0,0,14,15};
__device__ __constant__ int EDGE_B[19] = {8,9,10,11,12,13,2,3,4,16,5,6,7,17,1,14,15,16,17};

__device__ __forceinline__ unsigned short f2bf(float f) {
    unsigned int x = __float_as_uint(f);
    x += 0x7FFFu + ((x >> 16) & 1u);
    return (unsigned short)(x >> 16);
}

// XOR-swizzle on LDS byte offsets (preserves 16B granules). MASK=48 for
// 64B/pixel rows, 16 for 32B/pixel rows. Spreads a wave's lanes over all 8
// 16B granule positions -> near-conflict-free ds_read_b128.
template<int MASK>
__device__ __forceinline__ int sw(int lin) { return lin ^ ((lin >> 3) & MASK); }

// ---------------------------------------------------------------------------
// Weight pre-pass. Layouts (elem offsets in ws):
//   W1  @0     : 13 tp x 16 n x 32 k          6656  (16x16 paired, conv1)
//   W2n @6656  : 25 tap x 32 oc x 16 k       12800  (32x32, conv2)
//   W3n @19456 : 25 x 2 ich x 32 oc x 16 k   25600  (32x32, conv3)
//   W4n @45056 : 25 x 2 x 32 x 16            25600  (32x32, conv4)
//   W5  @70656 : 8 nt x 16 n x 32 k           4096  (16x16, conv5)
//   W0  @74752 : 4 c x 16 n x 32 k            2048  (16x16, conv0)
// total 76800 elems = 153600 B
// ---------------------------------------------------------------------------
extern "C" __global__ void __launch_bounds__(256)
reorder_weights(const float* __restrict__ w0, const float* __restrict__ w1,
                const float* __restrict__ w2, const float* __restrict__ w3,
                const float* __restrict__ w4, const float* __restrict__ w5,
                unsigned short* __restrict__ ws)
{
    int idx = blockIdx.x * 256 + threadIdx.x;
    if (idx < 6656) {
        int k = idx & 31, n = (idx >> 5) & 15, tp = idx >> 9;
        int t = 2 * tp + (k >> 4), ic = k & 15;
        float v = (t < 25) ? w1[(n * 16 + ic) * 25 + t] : 0.f;
        ws[idx] = f2bf(v);
    } else if (idx < 19456) {
        int j = idx - 6656;
        int tap = j >> 9, oc = (j >> 4) & 31, k = j & 15;
        ws[idx] = f2bf(w2[(oc * 16 + k) * 25 + tap]);
    } else if (idx < 45056) {
        int j = idx - 19456;
        int tap = j >> 10, ih = (j >> 9) & 1, oc = (j >> 4) & 31, k = j & 15;
        ws[idx] = f2bf(w3[(oc * 32 + ih * 16 + k) * 25 + tap]);
    } else if (idx < 70656) {
        int j = idx - 45056;
        int tap = j >> 10, ih = (j >> 9) & 1, oc = (j >> 4) & 31, k = j & 15;
        ws[idx] = f2bf(w4[(oc * 32 + ih * 16 + k) * 25 + tap]);
    } else if (idx < 74752) {
        int j = idx - 70656;
        int k = j & 31, oc = j >> 5;
        ws[idx] = f2bf(w5[oc * 32 + k]);
    } else if (idx < 76800) {
        int j = idx - 74752;
        int k = j & 31, n = (j >> 5) & 15, c = j >> 9;
        int t = c * 8 + (k >> 2), ic = k & 3;
        float v = (t < 25) ? w0[(n * 4 + ic) * 25 + t] : 0.f;
        ws[idx] = f2bf(v);
    }
}

__device__ __forceinline__ ushort4 pack_relu4(f32x4 a, float4 b, bool oob) {
    ushort4 us;
    us.x = oob ? 0 : f2bf(fmaxf(a[0] + b.x, 0.f));
    us.y = oob ? 0 : f2bf(fmaxf(a[1] + b.y, 0.f));
    us.z = oob ? 0 : f2bf(fmaxf(a[2] + b.z, 0.f));
    us.w = oob ? 0 : f2bf(fmaxf(a[3] + b.w, 0.f));
    return us;
}

// ---------------------------------------------------------------------------
// 5x5 conv stage on 32x32x16 MFMA: A=weights (M=32 oc, VGPR-resident in
// chunks, unroll-1 to stop hoisting), B=pixels (N=32, K=16 ic per instr).
// 2x MACs per LDS byte vs 16x16x32. D: col(lane&31)=pixel,
// row=(reg&3)+8*(reg>>2)+4*(lane>>5)=oc -> 4x b64 epilogue writes per lane.
// ---------------------------------------------------------------------------
template<int SIN, int SOUT, int CIN, int NTILE, int MAXM, bool GUARD, int CHUNK>
__device__ __forceinline__ void conv32(
    const unsigned char* __restrict__ sinB, unsigned char* __restrict__ soutB,
    const unsigned short* __restrict__ wA, const float* __restrict__ bias,
    int gy0, int gx0, int wave, int lane)
{
    constexpr int NPX   = SOUT * SOUT;
    constexpr int ICH   = CIN / 16;
    constexpr int RB    = CIN * 2;
    constexpr int IMASK = (CIN == 16) ? 16 : 48;
    const int n = lane & 31, half = lane >> 5;

    int pbase[MAXM], porig[MAXM];
#pragma unroll
    for (int i = 0; i < MAXM; ++i) {
        int nt = wave + 8 * i;
        int p = nt * 32 + n;
        porig[i] = p;
        int pc = (GUARD && p >= NPX) ? (NPX - 1) : p;   // clamp partial ntile
        int y = pc / SOUT, x = pc - y * SOUT;
        pbase[i] = (y * SIN + x) * RB + half * 16;
    }
    f32x16 acc[MAXM];
#pragma unroll
    for (int i = 0; i < MAXM; ++i) acc[i] = (f32x16)0.f;

    const unsigned short* wp = wA + n * 16 + half * 8;

#pragma unroll 1
    for (int c0 = 0; c0 < 25; c0 += CHUNK) {
        bf16x8 wf[CHUNK][ICH];
#pragma unroll
        for (int tp = 0; tp < CHUNK; ++tp)
            if (c0 + tp < 25)
#pragma unroll
                for (int ih = 0; ih < ICH; ++ih)
                    wf[tp][ih] = *(const bf16x8*)(wp + ((c0 + tp) * ICH + ih) * 512);
#pragma unroll
        for (int tp = 0; tp < CHUNK; ++tp) {
            if (c0 + tp < 25) {
                int t = c0 + tp;
                int dy = t / 5, dx = t - 5 * dy;
                int toff = (dy * SIN + dx) * RB;
#pragma unroll
                for (int ih = 0; ih < ICH; ++ih)
#pragma unroll
                    for (int i = 0; i < MAXM; ++i)
                        if (!GUARD || wave + 8 * i < NTILE) {
                            bf16x8 a = *(const bf16x8*)(sinB + sw<IMASK>(pbase[i] + toff + ih * 32));
                            acc[i] = __builtin_amdgcn_mfma_f32_32x32x16_bf16(wf[tp][ih], a, acc[i], 0, 0, 0);
                        }
            }
        }
    }

    float4 bb[4];
#pragma unroll
    for (int rg = 0; rg < 4; ++rg) bb[rg] = *(const float4*)(bias + 8 * rg + 4 * half);
#pragma unroll
    for (int i = 0; i < MAXM; ++i) {
        int nt = wave + 8 * i;
        if (!GUARD || nt < NTILE) {
            int p = porig[i];
            if (!GUARD || p < NPX) {
                int y = p / SOUT, x = p - y * SOUT;
                bool oob = ((unsigned)(gy0 + y) >= 128u) || ((unsigned)(gx0 + x) >= 128u);
#pragma unroll
                for (int rg = 0; rg < 4; ++rg) {
                    f32x4 a4;
                    a4[0] = acc[i][rg * 4 + 0]; a4[1] = acc[i][rg * 4 + 1];
                    a4[2] = acc[i][rg * 4 + 2]; a4[3] = acc[i][rg * 4 + 3];
                    int lin = p * 64 + rg * 16 + half * 8;
                    *(ushort4*)(soutB + sw<48>(lin)) = pack_relu4(a4, bb[rg], oob);
                }
            }
        }
    }
}

// ---------------------------------------------------------------------------
// conv1 (16->16) paired-tap 16x16x32 stage (kept from R5, unroll-1 chunks).
// ---------------------------------------------------------------------------
template<int SIN, int SOUT, int MAXM>
__device__ __forceinline__ void conv_paired16(
    const unsigned char* __restrict__ sinB, unsigned char* __restrict__ soutB,
    const unsigned short* __restrict__ wA, const float* __restrict__ bias,
    int gy0, int gx0, int wave, int lane)
{
    constexpr int NM = (SOUT * SOUT) / 16;
    const int nl = lane & 15, quad = lane >> 4;
    const int h = quad >> 1;
    const int coff = (quad & 1) * 16;

    int abase[MAXM];
#pragma unroll
    for (int i = 0; i < MAXM; ++i) {
        int mt = wave + 8 * i;
        if (mt < NM) {
            int p = mt * 16 + nl;
            int y = p / SOUT, x = p - y * SOUT;
            abase[i] = (y * SIN + x) * 32 + coff;
        }
    }
    f32x4 acc[MAXM];
#pragma unroll
    for (int i = 0; i < MAXM; ++i) acc[i] = (f32x4)0.f;

    const unsigned short* wp = wA + nl * 32 + quad * 8;

    bf16x8 wf[5];
#pragma unroll 1
    for (int c = 0; c < 3; ++c) {
        const int c0 = (c == 0) ? 0 : (c == 1) ? 5 : 10;
        const int cn = (c == 2) ? 3 : 5;
#pragma unroll
        for (int tp = 0; tp < 5; ++tp)
            if (tp < cn) wf[tp] = *(const bf16x8*)(wp + (c0 + tp) * 512);
#pragma unroll
        for (int tp = 0; tp < 5; ++tp) {
            if (tp < cn) {
                int t = 2 * (c0 + tp) + h;
                if (t > 24) t = 24;              // padded half; weights zero
                int dy = t / 5, dx = t - 5 * dy;
                int toff = (dy * SIN + dx) * 32;
#pragma unroll
                for (int i = 0; i < MAXM; ++i)
                    if (wave + 8 * i < NM) {
                        bf16x8 a = *(const bf16x8*)(sinB + sw<16>(abase[i] + toff));
                        acc[i] = __builtin_amdgcn_mfma_f32_16x16x32_bf16(wf[tp], a, acc[i], 0, 0, 0);
                    }
            }
        }
    }

    float4 bb = *(const float4*)(bias + quad * 4);
#pragma unroll
    for (int i = 0; i < MAXM; ++i) {
        int mt = wave + 8 * i;
        if (mt < NM) {
            int p = mt * 16 + nl;
            int y = p / SOUT, x = p - y * SOUT;
            bool oob = ((unsigned)(gy0 + y) >= 128u) || ((unsigned)(gx0 + x) >= 128u);
            int lin = p * 32 + quad * 8;
            *(ushort4*)(soutB + sw<16>(lin)) = pack_relu4(acc[i], bb, oob);
        }
    }
}

// ---------------------------------------------------------------------------
// Fused pipeline: one 512-thread block = one 16x16 output tile.
// LDS (65536 B): s_in@0 10368 | s0@32768 32768 | s1@0 25088 | s2@28672 36864
//                | s3@0 25600 | s4@49152 16384   (ping-pong, no overlaps)
// ---------------------------------------------------------------------------
extern "C" __global__ void __launch_bounds__(512, 4)
gnn_paf_mfma(const float* __restrict__ cnn, const unsigned short* __restrict__ wB,
             const float* __restrict__ b0, const float* __restrict__ b1,
             const float* __restrict__ b2, const float* __restrict__ b3,
             const float* __restrict__ b4, const float* __restrict__ b5,
             const float* __restrict__ w6, const float* __restrict__ b6,
             float* __restrict__ out)
{
    __shared__ __align__(64) unsigned char smem[65536];
    unsigned short* s_in = (unsigned short*)(smem);
    unsigned char*  s0   = smem + 32768;
    unsigned char*  s1   = smem;
    unsigned char*  s2   = smem + 28672;
    unsigned char*  s3   = smem;
    unsigned char*  s4   = smem + 49152;

    const int tid  = threadIdx.x;
    const int lane = tid & 63, wave = tid >> 6;
    const int tile = blockIdx.x, img = blockIdx.y;
    const int oy = (tile >> 3) * 16, ox = (tile & 7) * 16;
    const int n = img / 19, g = img - n * 19;
    const int ch0 = EDGE_A[g], ch1 = EDGE_B[g], ch2 = 19 + 2 * g, ch3 = 20 + 2 * g;
    const int nl = lane & 15, quad = lane >> 4;

    // ---- gather -> s_in bf16 HWC4 (36x36 halo, zero-padded)
    {
        const long long nb = (long long)n * 57 * 16384;
        for (int p = tid; p < 1296; p += 512) {
            int r = p / 36, col = p - r * 36;
            int gy = oy - 10 + r, gx = ox - 10 + col;
            ushort4 v = {0, 0, 0, 0};
            if ((unsigned)gy < 128u && (unsigned)gx < 128u) {
                int off = gy * 128 + gx;
                v.x = f2bf(cnn[nb + (long long)ch0 * 16384 + off]);
                v.y = f2bf(cnn[nb + (long long)ch1 * 16384 + off]);
                v.z = f2bf(cnn[nb + (long long)ch2 * 16384 + off]);
                v.w = f2bf(cnn[nb + (long long)ch3 * 16384 + off]);
            }
            *(ushort4*)(s_in + p * 4) = v;
        }
    }
    __syncthreads();

    // ---- conv0 (4->16) 16x16x32 MFMA: K=32 = 8 taps x 4 ch, 4 chunks
    {
        bf16x8 wf[4];
#pragma unroll
        for (int c = 0; c < 4; ++c)
            wf[c] = *(const bf16x8*)(wB + 74752 + c * 512 + nl * 32 + quad * 8);
        float4 bb = *(const float4*)(b0 + quad * 4);
#pragma unroll 1
        for (int i = 0; i < 8; ++i) {
            int mt = wave + 8 * i;                 // 64 mtiles
            int p = mt * 16 + nl;
            int y = p >> 5, x = p & 31;
            f32x4 acc = (f32x4)0.f;
#pragma unroll
            for (int c = 0; c < 4; ++c) {
                int t0 = c * 8 + quad * 2, t1 = t0 + 1;
                if (t0 > 24) t0 = 24;
                if (t1 > 24) t1 = 24;              // padded taps; weights zero
                int dy0 = t0 / 5, dx0 = t0 - 5 * dy0;
                int dy1 = t1 / 5, dx1 = t1 - 5 * dy1;
                uint2 lo = *(const uint2*)(s_in + ((y + dy0) * 36 + x + dx0) * 4);
                uint2 hi = *(const uint2*)(s_in + ((y + dy1) * 36 + x + dx1) * 4);
                bf16x8 a;
                ((uint2*)&a)[0] = lo;
                ((uint2*)&a)[1] = hi;
                acc = __builtin_amdgcn_mfma_f32_16x16x32_bf16(wf[c], a, acc, 0, 0, 0);
            }
            bool oob = ((unsigned)(oy - 8 + y) >= 128u) || ((unsigned)(ox - 8 + x) >= 128u);
            int lin = p * 32 + quad * 8;
            *(ushort4*)(s0 + sw<16>(lin)) = pack_relu4(acc, bb, oob);
        }
    }
    __syncthreads();

    conv_paired16<32, 28, 7>(s0, s1, wB + 0, b1, oy - 6, ox - 6, wave, lane);
    __syncthreads();
    conv32<28, 24, 16, 18, 3, true,  5>(s1, s2, wB + 6656,  b2, oy - 4, ox - 4, wave, lane);
    __syncthreads();
    conv32<24, 20, 32, 13, 2, true,  3>(s2, s3, wB + 19456, b3, oy - 2, ox - 2, wave, lane);
    __syncthreads();
    conv32<20, 16, 32,  8, 1, false, 3>(s3, s4, wB + 45056, b4, oy,     ox,     wave, lane);
    __syncthreads();

    // ---- conv5 (1x1 32->128) 16x16x32 + relu + conv6 (128->2)
    {
        bf16x8 w5f[8];
#pragma unroll
        for (int nt = 0; nt < 8; ++nt)
            w5f[nt] = *(const bf16x8*)(wB + 70656 + nt * 512 + nl * 32 + quad * 8);
        const float b6q = b6[quad & 1];
#pragma unroll 1
        for (int ii = 0; ii < 2; ++ii) {
            int mt = wave + 8 * ii;                // 16 mtiles
            int lin = (mt * 16 + nl) * 64 + quad * 16;
            bf16x8 pf = *(const bf16x8*)(s4 + sw<48>(lin));
            float o0 = 0.f, o1 = 0.f;
#pragma unroll
            for (int nt = 0; nt < 8; ++nt) {
                f32x4 acc = (f32x4)0.f;
                acc = __builtin_amdgcn_mfma_f32_16x16x32_bf16(w5f[nt], pf, acc, 0, 0, 0);
                float4 bb  = *(const float4*)(b5 + nt * 16 + quad * 4);
                float4 wa  = *(const float4*)(w6 + nt * 16 + quad * 4);
                float4 wb2 = *(const float4*)(w6 + 128 + nt * 16 + quad * 4);
                float h0 = fmaxf(acc[0] + bb.x, 0.f), h1 = fmaxf(acc[1] + bb.y, 0.f);
                float h2 = fmaxf(acc[2] + bb.z, 0.f), h3 = fmaxf(acc[3] + bb.w, 0.f);
                o0 = fmaf(h0, wa.x, fmaf(h1, wa.y, fmaf(h2, wa.z, fmaf(h3, wa.w, o0))));
                o1 = fmaf(h0, wb2.x, fmaf(h1, wb2.y, fmaf(h2, wb2.z, fmaf(h3, wb2.w, o1))));
            }
            o0 += __shfl_xor(o0, 16, 64); o0 += __shfl_xor(o0, 32, 64);
            o1 += __shfl_xor(o1, 16, 64); o1 += __shfl_xor(o1, 32, 64);
            if (quad < 2) {
                float val = ((quad == 0) ? o0 : o1) + b6q;
                long long ob = (((long long)n * 38 + 2 * g + quad) * 128 + (oy + mt)) * 128 + (ox + nl);
                out[ob] = val;
            }
        }
    }
}

extern "C" void kernel_launch(void* const* d_in, const int* in_sizes, int n_in,
                              void* d_out, int out_size, void* d_ws, size_t ws_size,
                              hipStream_t stream) {
    const float* cnn = (const float*)d_in[0];
    const float* w0 = (const float*)d_in[2];  const float* b0 = (const float*)d_in[3];
    const float* w1 = (const float*)d_in[4];  const float* b1 = (const float*)d_in[5];
    const float* w2 = (const float*)d_in[6];  const float* b2 = (const float*)d_in[7];
    const float* w3 = (const float*)d_in[8];  const float* b3 = (const float*)d_in[9];
    const float* w4 = (const float*)d_in[10]; const float* b4 = (const float*)d_in[11];
    const float* w5 = (const float*)d_in[12]; const float* b5 = (const float*)d_in[13];
    const float* w6 = (const float*)d_in[14]; const float* b6 = (const float*)d_in[15];
    float* out = (float*)d_out;
    unsigned short* wB = (unsigned short*)d_ws;   // 153600 B used

    hipLaunchKernelGGL(reorder_weights, dim3(300), dim3(256), 0, stream,
                       w0, w1, w2, w3, w4, w5, wB);
    hipLaunchKernelGGL(gnn_paf_mfma, dim3(64, 304), dim3(512), 0, stream,
                       cnn, wB, b0, b1, b2, b3, b4, b5, w6, b6, out);
}

// Round 7
// 2161.326 us; speedup vs baseline: 1.2553x; 1.2553x over previous
//
#include <hip/hip_runtime.h>

typedef __bf16  bf16x8 __attribute__((ext_vector_type(8)));
typedef float   f32x4  __attribute__((ext_vector_type(4)));

__device__ __constant__ int EDGE_A[19] = {1,8,9,1,11,12,1,2,3,2,1,5,6,5,0,0,0,14,15};
__device__ __constant__ int EDGE_B[19] = {8,9,10,11,12,13,2,3,4,16,5,6,7,17,1,14,15,16,17};

__device__ __forceinline__ unsigned short f2bf(float f) {
    unsigned int x = __float_as_uint(f);
    x += 0x7FFFu + ((x >> 16) & 1u);
    return (unsigned short)(x >> 16);
}

// XOR-swizzle on LDS byte offsets (16B-granule-preserving).
template<int MASK>
__device__ __forceinline__ int sw(int lin) { return lin ^ ((lin >> 3) & MASK); }

// ---------------------------------------------------------------------------
// Weight pre-pass -> A-fragment layout (lane m=oc=idx&15 holds k=quad*8+j).
//   W1 @0     : 13 tap-pairs x 1 x 16 x 32   6656   (k = h*16+ic, t=2tp+h)
//   W2 @6656  : 13 x 2 x 16 x 32            13312
//   W3 @19968 : 25 taps x 2 x 16 x 32       25600   (k = ic)
//   W4 @45568 : 25 x 2 x 16 x 32            25600
//   W5 @71168 : 8 x 16 x 32                  4096
//   W0 @75264 : 4 chunks x 16 x 32           2048   (k = tl*4+ic, t=c*8+tl)
// ---------------------------------------------------------------------------
extern "C" __global__ void __launch_bounds__(256)
reorder_weights(const float* __restrict__ w0, const float* __restrict__ w1,
                const float* __restrict__ w2, const float* __restrict__ w3,
                const float* __restrict__ w4, const float* __restrict__ w5,
                unsigned short* __restrict__ ws)
{
    int idx = blockIdx.x * 256 + threadIdx.x;
    if (idx < 6656) {
        int k = idx & 31, n = (idx >> 5) & 15, tp = idx >> 9;
        int t = 2 * tp + (k >> 4), ic = k & 15;
        float v = (t < 25) ? w1[(n * 16 + ic) * 25 + t] : 0.f;
        ws[idx] = f2bf(v);
    } else if (idx < 19968) {
        int j = idx - 6656;
        int k = j & 31, n = (j >> 5) & 15, nt = (j >> 9) & 1, tp = j >> 10;
        int t = 2 * tp + (k >> 4), ic = k & 15, oc = nt * 16 + n;
        float v = (t < 25) ? w2[(oc * 16 + ic) * 25 + t] : 0.f;
        ws[idx] = f2bf(v);
    } else if (idx < 45568) {
        int j = idx - 19968;
        int k = j & 31, n = (j >> 5) & 15, nt = (j >> 9) & 1, tap = j >> 10;
        ws[idx] = f2bf(w3[((nt * 16 + n) * 32 + k) * 25 + tap]);
    } else if (idx < 71168) {
        int j = idx - 45568;
        int k = j & 31, n = (j >> 5) & 15, nt = (j >> 9) & 1, tap = j >> 10;
        ws[idx] = f2bf(w4[((nt * 16 + n) * 32 + k) * 25 + tap]);
    } else if (idx < 75264) {
        int j = idx - 71168;
        int k = j & 31, oc = j >> 5;
        ws[idx] = f2bf(w5[oc * 32 + k]);
    } else if (idx < 77312) {
        int j = idx - 75264;
        int k = j & 31, n = (j >> 5) & 15, c = j >> 9;
        int t = c * 8 + (k >> 2), ic = k & 3;
        float v = (t < 25) ? w0[(n * 4 + ic) * 25 + t] : 0.f;
        ws[idx] = f2bf(v);
    }
}

__device__ __forceinline__ ushort4 pack_relu4(f32x4 a, float4 b, bool oob) {
    ushort4 us;
    us.x = oob ? 0 : f2bf(fmaxf(a[0] + b.x, 0.f));
    us.y = oob ? 0 : f2bf(fmaxf(a[1] + b.y, 0.f));
    us.z = oob ? 0 : f2bf(fmaxf(a[2] + b.z, 0.f));
    us.w = oob ? 0 : f2bf(fmaxf(a[3] + b.w, 0.f));
    return us;
}

// ---------------------------------------------------------------------------
// Paired-tap 5x5 stage (CIN=16), 16x16x32, nt-FUSED: one A-fragment read per
// (mtile,tap) feeds all NT oc-tiles. Weight chunks (CH taps in flight) behind
// #pragma unroll 1 so they are NOT hoisted -> no spills.
// ---------------------------------------------------------------------------
template<int SIN, int SOUT, int NT, int MAXM, bool GUARD, int CH>
__device__ __forceinline__ void conv_p16(
    const unsigned char* __restrict__ sinB, unsigned char* __restrict__ soutB,
    const unsigned short* __restrict__ wA, const float* __restrict__ bias,
    int gy0, int gx0, int wave, int lane)
{
    constexpr int NM    = (SOUT * SOUT) / 16;
    constexpr int OMASK = (NT == 1) ? 16 : 48;
    const int nl = lane & 15, quad = lane >> 4;
    const int h = quad >> 1;
    const int coff = (quad & 1) * 16;

    int abase[MAXM];
#pragma unroll
    for (int i = 0; i < MAXM; ++i) {
        int mt = wave + 8 * i;
        if (!GUARD || mt < NM) {
            int p = mt * 16 + nl;
            int y = p / SOUT, x = p - y * SOUT;
            abase[i] = (y * SIN + x) * 32 + coff;
        }
    }
    f32x4 acc[MAXM][NT];
#pragma unroll
    for (int i = 0; i < MAXM; ++i)
#pragma unroll
        for (int nt = 0; nt < NT; ++nt) acc[i][nt] = (f32x4)0.f;

    const unsigned short* wp = wA + nl * 32 + quad * 8;

#pragma unroll 1
    for (int c0 = 0; c0 < 13; c0 += CH) {
        bf16x8 wf[CH][NT];
#pragma unroll
        for (int tp = 0; tp < CH; ++tp)
            if (c0 + tp < 13)
#pragma unroll
                for (int nt = 0; nt < NT; ++nt)
                    wf[tp][nt] = *(const bf16x8*)(wp + ((c0 + tp) * NT + nt) * 512);
#pragma unroll
        for (int tp = 0; tp < CH; ++tp) {
            if (c0 + tp < 13) {
                int t = 2 * (c0 + tp) + h;
                if (t > 24) t = 24;              // padded half; weights zero
                int dy = t / 5, dx = t - 5 * dy;
                int toff = (dy * SIN + dx) * 32;
#pragma unroll
                for (int i = 0; i < MAXM; ++i)
                    if (!GUARD || wave + 8 * i < NM) {
                        bf16x8 a = *(const bf16x8*)(sinB + sw<16>(abase[i] + toff));
#pragma unroll
                        for (int nt = 0; nt < NT; ++nt)
                            acc[i][nt] = __builtin_amdgcn_mfma_f32_16x16x32_bf16(wf[tp][nt], a, acc[i][nt], 0, 0, 0);
                    }
            }
        }
    }

#pragma unroll
    for (int i = 0; i < MAXM; ++i) {
        int mt = wave + 8 * i;
        if (!GUARD || mt < NM) {
            int p = mt * 16 + nl;
            int y = p / SOUT, x = p - y * SOUT;
            bool oob = ((unsigned)(gy0 + y) >= 128u) || ((unsigned)(gx0 + x) >= 128u);
#pragma unroll
            for (int nt = 0; nt < NT; ++nt) {
                float4 bb = *(const float4*)(bias + nt * 16 + quad * 4);
                int lin = p * (NT * 32) + nt * 32 + quad * 8;
                *(ushort4*)(soutB + sw<OMASK>(lin)) = pack_relu4(acc[i][nt], bb, oob);
            }
        }
    }
}

// ---------------------------------------------------------------------------
// CIN=32 5x5 stage (K=32 ic), nt-FUSED, chunked weights (unroll-1).
// ---------------------------------------------------------------------------
template<int SIN, int SOUT, int MAXM, bool GUARD, int CH>
__device__ __forceinline__ void conv_c32f(
    const unsigned char* __restrict__ sinB, unsigned char* __restrict__ soutB,
    const unsigned short* __restrict__ wA, const float* __restrict__ bias,
    int gy0, int gx0, int wave, int lane)
{
    constexpr int NM = (SOUT * SOUT) / 16;
    const int nl = lane & 15, quad = lane >> 4;

    int abase[MAXM];
#pragma unroll
    for (int i = 0; i < MAXM; ++i) {
        int mt = wave + 8 * i;
        if (!GUARD || mt < NM) {
            int p = mt * 16 + nl;
            int y = p / SOUT, x = p - y * SOUT;
            abase[i] = (y * SIN + x) * 64 + quad * 16;
        }
    }
    f32x4 acc[MAXM][2];
#pragma unroll
    for (int i = 0; i < MAXM; ++i) {
        acc[i][0] = (f32x4)0.f;
        acc[i][1] = (f32x4)0.f;
    }

    const unsigned short* wp = wA + nl * 32 + quad * 8;

#pragma unroll 1
    for (int c0 = 0; c0 < 25; c0 += CH) {
        bf16x8 wf[CH][2];
#pragma unroll
        for (int tp = 0; tp < CH; ++tp)
            if (c0 + tp < 25) {
                wf[tp][0] = *(const bf16x8*)(wp + ((c0 + tp) * 2 + 0) * 512);
                wf[tp][1] = *(const bf16x8*)(wp + ((c0 + tp) * 2 + 1) * 512);
            }
#pragma unroll
        for (int tp = 0; tp < CH; ++tp) {
            if (c0 + tp < 25) {
                int t = c0 + tp;
                int dy = t / 5, dx = t - 5 * dy;
                int toff = (dy * SIN + dx) * 64;
#pragma unroll
                for (int i = 0; i < MAXM; ++i)
                    if (!GUARD || wave + 8 * i < NM) {
                        bf16x8 a = *(const bf16x8*)(sinB + sw<48>(abase[i] + toff));
                        acc[i][0] = __builtin_amdgcn_mfma_f32_16x16x32_bf16(wf[tp][0], a, acc[i][0], 0, 0, 0);
                        acc[i][1] = __builtin_amdgcn_mfma_f32_16x16x32_bf16(wf[tp][1], a, acc[i][1], 0, 0, 0);
                    }
            }
        }
    }

#pragma unroll
    for (int i = 0; i < MAXM; ++i) {
        int mt = wave + 8 * i;
        if (!GUARD || mt < NM) {
            int p = mt * 16 + nl;
            int y = p / SOUT, x = p - y * SOUT;
            bool oob = ((unsigned)(gy0 + y) >= 128u) || ((unsigned)(gx0 + x) >= 128u);
#pragma unroll
            for (int nt = 0; nt < 2; ++nt) {
                float4 bb = *(const float4*)(bias + nt * 16 + quad * 4);
                int lin = p * 64 + nt * 32 + quad * 8;
                *(ushort4*)(soutB + sw<48>(lin)) = pack_relu4(acc[i][nt], bb, oob);
            }
        }
    }
}

// ---------------------------------------------------------------------------
// Fused pipeline: one 512-thread block = one 16x16 output tile.
// LDS (65536 B): s_in@0 10368 | s0@32768 32768 | s1@0 25088 | s2@28672 36864
//                | s3@0 25600 | s4@49152 16384   (ping-pong, no overlaps)
// ---------------------------------------------------------------------------
extern "C" __global__ void __launch_bounds__(512, 4)
gnn_paf_mfma(const float* __restrict__ cnn, const unsigned short* __restrict__ wB,
             const float* __restrict__ b0, const float* __restrict__ b1,
             const float* __restrict__ b2, const float* __restrict__ b3,
             const float* __restrict__ b4, const float* __restrict__ b5,
             const float* __restrict__ w6, const float* __restrict__ b6,
             float* __restrict__ out)
{
    __shared__ __align__(64) unsigned char smem[65536];
    unsigned short* s_in = (unsigned short*)(smem);
    unsigned char*  s0   = smem + 32768;
    unsigned char*  s1   = smem;
    unsigned char*  s2   = smem + 28672;
    unsigned char*  s3   = smem;
    unsigned char*  s4   = smem + 49152;

    const int tid  = threadIdx.x;
    const int lane = tid & 63, wave = tid >> 6;
    const int tile = blockIdx.x, img = blockIdx.y;
    const int oy = (tile >> 3) * 16, ox = (tile & 7) * 16;
    const int n = img / 19, g = img - n * 19;
    const int ch0 = EDGE_A[g], ch1 = EDGE_B[g], ch2 = 19 + 2 * g, ch3 = 20 + 2 * g;
    const int nl = lane & 15, quad = lane >> 4;

    // ---- gather -> s_in bf16 HWC4 (36x36 halo, zero-padded)
    {
        const long long nb = (long long)n * 57 * 16384;
        for (int p = tid; p < 1296; p += 512) {
            int r = p / 36, col = p - r * 36;
            int gy = oy - 10 + r, gx = ox - 10 + col;
            ushort4 v = {0, 0, 0, 0};
            if ((unsigned)gy < 128u && (unsigned)gx < 128u) {
                int off = gy * 128 + gx;
                v.x = f2bf(cnn[nb + (long long)ch0 * 16384 + off]);
                v.y = f2bf(cnn[nb + (long long)ch1 * 16384 + off]);
                v.z = f2bf(cnn[nb + (long long)ch2 * 16384 + off]);
                v.w = f2bf(cnn[nb + (long long)ch3 * 16384 + off]);
            }
            *(ushort4*)(s_in + p * 4) = v;
        }
    }
    __syncthreads();

    // ---- conv0 (4->16) 16x16x32 MFMA: K=32 = 8 taps x 4 ch, 4 chunks
    {
        bf16x8 wf[4];
#pragma unroll
        for (int c = 0; c < 4; ++c)
            wf[c] = *(const bf16x8*)(wB + 75264 + c * 512 + nl * 32 + quad * 8);
        float4 bb = *(const float4*)(b0 + quad * 4);
#pragma unroll 1
        for (int i = 0; i < 8; ++i) {
            int mt = wave + 8 * i;                 // 64 mtiles
            int p = mt * 16 + nl;
            int y = p >> 5, x = p & 31;
            f32x4 acc = (f32x4)0.f;
#pragma unroll
            for (int c = 0; c < 4; ++c) {
                int t0 = c * 8 + quad * 2, t1 = t0 + 1;
                if (t0 > 24) t0 = 24;
                if (t1 > 24) t1 = 24;              // padded taps; weights zero
                int dy0 = t0 / 5, dx0 = t0 - 5 * dy0;
                int dy1 = t1 / 5, dx1 = t1 - 5 * dy1;
                uint2 lo = *(const uint2*)(s_in + ((y + dy0) * 36 + x + dx0) * 4);
                uint2 hi = *(const uint2*)(s_in + ((y + dy1) * 36 + x + dx1) * 4);
                bf16x8 a;
                ((uint2*)&a)[0] = lo;
                ((uint2*)&a)[1] = hi;
                acc = __builtin_amdgcn_mfma_f32_16x16x32_bf16(wf[c], a, acc, 0, 0, 0);
            }
            bool oob = ((unsigned)(oy - 8 + y) >= 128u) || ((unsigned)(ox - 8 + x) >= 128u);
            int lin = p * 32 + quad * 8;
            *(ushort4*)(s0 + sw<16>(lin)) = pack_relu4(acc, bb, oob);
        }
    }
    __syncthreads();

    conv_p16<32, 28, 1, 7, true, 5>(s0, s1, wB + 0,     b1, oy - 6, ox - 6, wave, lane);
    __syncthreads();
    conv_p16<28, 24, 2, 5, true, 3>(s1, s2, wB + 6656,  b2, oy - 4, ox - 4, wave, lane);
    __syncthreads();
    conv_c32f<24, 20, 4, true,  3>(s2, s3, wB + 19968, b3, oy - 2, ox - 2, wave, lane);
    __syncthreads();
    conv_c32f<20, 16, 2, false, 3>(s3, s4, wB + 45568, b4, oy,     ox,     wave, lane);
    __syncthreads();

    // ---- conv5 (1x1 32->128) 16x16x32 + relu + conv6 (128->2)
    {
        bf16x8 w5f[8];
#pragma unroll
        for (int nt = 0; nt < 8; ++nt)
            w5f[nt] = *(const bf16x8*)(wB + 71168 + nt * 512 + nl * 32 + quad * 8);
        const float b6q = b6[quad & 1];
#pragma unroll 1
        for (int ii = 0; ii < 2; ++ii) {
            int mt = wave + 8 * ii;                // 16 mtiles
            int lin = (mt * 16 + nl) * 64 + quad * 16;
            bf16x8 pf = *(const bf16x8*)(s4 + sw<48>(lin));
            float o0 = 0.f, o1 = 0.f;
#pragma unroll
            for (int nt = 0; nt < 8; ++nt) {
                f32x4 acc = (f32x4)0.f;
                acc = __builtin_amdgcn_mfma_f32_16x16x32_bf16(w5f[nt], pf, acc, 0, 0, 0);
                float4 bb  = *(const float4*)(b5 + nt * 16 + quad * 4);
                float4 wa  = *(const float4*)(w6 + nt * 16 + quad * 4);
                float4 wb2 = *(const float4*)(w6 + 128 + nt * 16 + quad * 4);
                float h0 = fmaxf(acc[0] + bb.x, 0.f), h1 = fmaxf(acc[1] + bb.y, 0.f);
                float h2 = fmaxf(acc[2] + bb.z, 0.f), h3 = fmaxf(acc[3] + bb.w, 0.f);
                o0 = fmaf(h0, wa.x, fmaf(h1, wa.y, fmaf(h2, wa.z, fmaf(h3, wa.w, o0))));
                o1 = fmaf(h0, wb2.x, fmaf(h1, wb2.y, fmaf(h2, wb2.z, fmaf(h3, wb2.w, o1))));
            }
            o0 += __shfl_xor(o0, 16, 64); o0 += __shfl_xor(o0, 32, 64);
            o1 += __shfl_xor(o1, 16, 64); o1 += __shfl_xor(o1, 32, 64);
            if (quad < 2) {
                float val = ((quad == 0) ? o0 : o1) + b6q;
                long long ob = (((long long)n * 38 + 2 * g + quad) * 128 + (oy + mt)) * 128 + (ox + nl);
                out[ob] = val;
            }
        }
    }
}

extern "C" void kernel_launch(void* const* d_in, const int* in_sizes, int n_in,
                              void* d_out, int out_size, void* d_ws, size_t ws_size,
                              hipStream_t stream) {
    const float* cnn = (const float*)d_in[0];
    const float* w0 = (const float*)d_in[2];  const float* b0 = (const float*)d_in[3];
    const float* w1 = (const float*)d_in[4];  const float* b1 = (const float*)d_in[5];
    const float* w2 = (const float*)d_in[6];  const float* b2 = (const float*)d_in[7];
    const float* w3 = (const float*)d_in[8];  const float* b3 = (const float*)d_in[9];
    const float* w4 = (const float*)d_in[10]; const float* b4 = (const float*)d_in[11];
    const float* w5 = (const float*)d_in[12]; const float* b5 = (const float*)d_in[13];
    const float* w6 = (const float*)d_in[14]; const float* b6 = (const float*)d_in[15];
    float* out = (float*)d_out;
    unsigned short* wB = (unsigned short*)d_ws;   // 154,624 B used

    hipLaunchKernelGGL(reorder_weights, dim3(302), dim3(256), 0, stream,
                       w0, w1, w2, w3, w4, w5, wB);
    hipLaunchKernelGGL(gnn_paf_mfma, dim3(64, 304), dim3(512), 0, stream,
                       cnn, wB, b0, b1, b2, b3, b4, b5, w6, b6, out);
}

// Round 8
// 1868.462 us; speedup vs baseline: 1.4520x; 1.1567x over previous
//
#include <hip/hip_runtime.h>

typedef __bf16  bf16x8 __attribute__((ext_vector_type(8)));
typedef float   f32x4  __attribute__((ext_vector_type(4)));

__device__ __constant__ int EDGE_A[19] = {1,8,9,1,11,12,1,2,3,2,1,5,6,5,0,0,0,14,15};
__device__ __constant__ int EDGE_B[19] = {8,9,10,11,12,13,2,3,4,16,5,6,7,17,1,14,15,16,17};

__device__ __forceinline__ unsigned short f2bf(float f) {
    unsigned int x = __float_as_uint(f);
    x += 0x7FFFu + ((x >> 16) & 1u);
    return (unsigned short)(x >> 16);
}

// XOR-swizzle on LDS byte offsets (16B-granule-preserving).
template<int MASK>
__device__ __forceinline__ int sw(int lin) { return lin ^ ((lin >> 3) & MASK); }

// ---------------------------------------------------------------------------
// Weight pre-pass -> A-fragment layout (lane m=oc=idx&15 holds k=quad*8+j).
//   W1 @0     : 13 tap-pairs x 1 x 16 x 32   6656   (k = h*16+ic, t=2tp+h)
//   W2 @6656  : 13 x 2 x 16 x 32            13312
//   W3 @19968 : 25 taps x 2 x 16 x 32       25600   (k = ic)
//   W4 @45568 : 25 x 2 x 16 x 32            25600
//   W5 @71168 : 8 x 16 x 32                  4096
//   W0 @75264 : 4 chunks x 16 x 32           2048   (k = tl*4+ic, t=c*8+tl)
// ---------------------------------------------------------------------------
extern "C" __global__ void __launch_bounds__(256)
reorder_weights(const float* __restrict__ w0, const float* __restrict__ w1,
                const float* __restrict__ w2, const float* __restrict__ w3,
                const float* __restrict__ w4, const float* __restrict__ w5,
                unsigned short* __restrict__ ws)
{
    int idx = blockIdx.x * 256 + threadIdx.x;
    if (idx < 6656) {
        int k = idx & 31, n = (idx >> 5) & 15, tp = idx >> 9;
        int t = 2 * tp + (k >> 4), ic = k & 15;
        float v = (t < 25) ? w1[(n * 16 + ic) * 25 + t] : 0.f;
        ws[idx] = f2bf(v);
    } else if (idx < 19968) {
        int j = idx - 6656;
        int k = j & 31, n = (j >> 5) & 15, nt = (j >> 9) & 1, tp = j >> 10;
        int t = 2 * tp + (k >> 4), ic = k & 15, oc = nt * 16 + n;
        float v = (t < 25) ? w2[(oc * 16 + ic) * 25 + t] : 0.f;
        ws[idx] = f2bf(v);
    } else if (idx < 45568) {
        int j = idx - 19968;
        int k = j & 31, n = (j >> 5) & 15, nt = (j >> 9) & 1, tap = j >> 10;
        ws[idx] = f2bf(w3[((nt * 16 + n) * 32 + k) * 25 + tap]);
    } else if (idx < 71168) {
        int j = idx - 45568;
        int k = j & 31, n = (j >> 5) & 15, nt = (j >> 9) & 1, tap = j >> 10;
        ws[idx] = f2bf(w4[((nt * 16 + n) * 32 + k) * 25 + tap]);
    } else if (idx < 75264) {
        int j = idx - 71168;
        int k = j & 31, oc = j >> 5;
        ws[idx] = f2bf(w5[oc * 32 + k]);
    } else if (idx < 77312) {
        int j = idx - 75264;
        int k = j & 31, n = (j >> 5) & 15, c = j >> 9;
        int t = c * 8 + (k >> 2), ic = k & 3;
        float v = (t < 25) ? w0[(n * 4 + ic) * 25 + t] : 0.f;
        ws[idx] = f2bf(v);
    }
}

__device__ __forceinline__ ushort4 pack_relu4(f32x4 a, float4 b, bool oob) {
    ushort4 us;
    us.x = oob ? 0 : f2bf(fmaxf(a[0] + b.x, 0.f));
    us.y = oob ? 0 : f2bf(fmaxf(a[1] + b.y, 0.f));
    us.z = oob ? 0 : f2bf(fmaxf(a[2] + b.z, 0.f));
    us.w = oob ? 0 : f2bf(fmaxf(a[3] + b.w, 0.f));
    return us;
}

// ---------------------------------------------------------------------------
// Paired-tap 5x5 stage (CIN=16), 16x16x32, nt-fused. 4 waves, stride-4 mtiles.
// 256-reg budget (launch_bounds 256,2) -> whole live set in registers.
// ---------------------------------------------------------------------------
template<int SIN, int SOUT, int NT, int MAXM, bool GUARD, int CH>
__device__ __forceinline__ void conv_p16(
    const unsigned char* __restrict__ sinB, unsigned char* __restrict__ soutB,
    const unsigned short* __restrict__ wA, const float* __restrict__ bias,
    int gy0, int gx0, int wave, int lane)
{
    constexpr int NM    = (SOUT * SOUT) / 16;
    constexpr int OMASK = (NT == 1) ? 16 : 48;
    const int nl = lane & 15, quad = lane >> 4;
    const int h = quad >> 1;
    const int coff = (quad & 1) * 16;

    int abase[MAXM];
#pragma unroll
    for (int i = 0; i < MAXM; ++i) {
        int mt = wave + 4 * i;
        if (!GUARD || mt < NM) {
            int p = mt * 16 + nl;
            int y = p / SOUT, x = p - y * SOUT;
            abase[i] = (y * SIN + x) * 32 + coff;
        }
    }
    f32x4 acc[MAXM][NT];
#pragma unroll
    for (int i = 0; i < MAXM; ++i)
#pragma unroll
        for (int nt = 0; nt < NT; ++nt) acc[i][nt] = (f32x4)0.f;

    const unsigned short* wp = wA + nl * 32 + quad * 8;

#pragma unroll 1
    for (int c0 = 0; c0 < 13; c0 += CH) {
        bf16x8 wf[CH][NT];
#pragma unroll
        for (int tp = 0; tp < CH; ++tp)
            if (c0 + tp < 13)
#pragma unroll
                for (int nt = 0; nt < NT; ++nt)
                    wf[tp][nt] = *(const bf16x8*)(wp + ((c0 + tp) * NT + nt) * 512);
#pragma unroll
        for (int tp = 0; tp < CH; ++tp) {
            if (c0 + tp < 13) {
                int t = 2 * (c0 + tp) + h;
                if (t > 24) t = 24;              // padded half; weights zero
                int dy = t / 5, dx = t - 5 * dy;
                int toff = (dy * SIN + dx) * 32;
#pragma unroll
                for (int i = 0; i < MAXM; ++i)
                    if (!GUARD || wave + 4 * i < NM) {
                        bf16x8 a = *(const bf16x8*)(sinB + sw<16>(abase[i] + toff));
#pragma unroll
                        for (int nt = 0; nt < NT; ++nt)
                            acc[i][nt] = __builtin_amdgcn_mfma_f32_16x16x32_bf16(wf[tp][nt], a, acc[i][nt], 0, 0, 0);
                    }
            }
        }
    }

#pragma unroll
    for (int i = 0; i < MAXM; ++i) {
        int mt = wave + 4 * i;
        if (!GUARD || mt < NM) {
            int p = mt * 16 + nl;
            int y = p / SOUT, x = p - y * SOUT;
            bool oob = ((unsigned)(gy0 + y) >= 128u) || ((unsigned)(gx0 + x) >= 128u);
#pragma unroll
            for (int nt = 0; nt < NT; ++nt) {
                float4 bb = *(const float4*)(bias + nt * 16 + quad * 4);
                int lin = p * (NT * 32) + nt * 32 + quad * 8;
                *(ushort4*)(soutB + sw<OMASK>(lin)) = pack_relu4(acc[i][nt], bb, oob);
            }
        }
    }
}

// ---------------------------------------------------------------------------
// CIN=32 5x5 stage (K=32 ic), nt-fused, chunked weights. 4 waves, stride 4.
// ---------------------------------------------------------------------------
template<int SIN, int SOUT, int MAXM, bool GUARD, int CH>
__device__ __forceinline__ void conv_c32f(
    const unsigned char* __restrict__ sinB, unsigned char* __restrict__ soutB,
    const unsigned short* __restrict__ wA, const float* __restrict__ bias,
    int gy0, int gx0, int wave, int lane)
{
    constexpr int NM = (SOUT * SOUT) / 16;
    const int nl = lane & 15, quad = lane >> 4;

    int abase[MAXM];
#pragma unroll
    for (int i = 0; i < MAXM; ++i) {
        int mt = wave + 4 * i;
        if (!GUARD || mt < NM) {
            int p = mt * 16 + nl;
            int y = p / SOUT, x = p - y * SOUT;
            abase[i] = (y * SIN + x) * 64 + quad * 16;
        }
    }
    f32x4 acc[MAXM][2];
#pragma unroll
    for (int i = 0; i < MAXM; ++i) {
        acc[i][0] = (f32x4)0.f;
        acc[i][1] = (f32x4)0.f;
    }

    const unsigned short* wp = wA + nl * 32 + quad * 8;

#pragma unroll 1
    for (int c0 = 0; c0 < 25; c0 += CH) {
        bf16x8 wf[CH][2];
#pragma unroll
        for (int tp = 0; tp < CH; ++tp)
            if (c0 + tp < 25) {
                wf[tp][0] = *(const bf16x8*)(wp + ((c0 + tp) * 2 + 0) * 512);
                wf[tp][1] = *(const bf16x8*)(wp + ((c0 + tp) * 2 + 1) * 512);
            }
#pragma unroll
        for (int tp = 0; tp < CH; ++tp) {
            if (c0 + tp < 25) {
                int t = c0 + tp;
                int dy = t / 5, dx = t - 5 * dy;
                int toff = (dy * SIN + dx) * 64;
#pragma unroll
                for (int i = 0; i < MAXM; ++i)
                    if (!GUARD || wave + 4 * i < NM) {
                        bf16x8 a = *(const bf16x8*)(sinB + sw<48>(abase[i] + toff));
                        acc[i][0] = __builtin_amdgcn_mfma_f32_16x16x32_bf16(wf[tp][0], a, acc[i][0], 0, 0, 0);
                        acc[i][1] = __builtin_amdgcn_mfma_f32_16x16x32_bf16(wf[tp][1], a, acc[i][1], 0, 0, 0);
                    }
            }
        }
    }

#pragma unroll
    for (int i = 0; i < MAXM; ++i) {
        int mt = wave + 4 * i;
        if (!GUARD || mt < NM) {
            int p = mt * 16 + nl;
            int y = p / SOUT, x = p - y * SOUT;
            bool oob = ((unsigned)(gy0 + y) >= 128u) || ((unsigned)(gx0 + x) >= 128u);
#pragma unroll
            for (int nt = 0; nt < 2; ++nt) {
                float4 bb = *(const float4*)(bias + nt * 16 + quad * 4);
                int lin = p * 64 + nt * 32 + quad * 8;
                *(ushort4*)(soutB + sw<48>(lin)) = pack_relu4(acc[i][nt], bb, oob);
            }
        }
    }
}

// ---------------------------------------------------------------------------
// Fused pipeline: one 256-thread block (4 waves) = one 16x16 output tile.
// launch_bounds(256,2): 256-reg waves (spill-free), 2 blocks/CU (LDS-capped).
// LDS (65536 B): s_in@0 10368 | s0@32768 32768 | s1@0 25088 | s2@28672 36864
//                | s3@0 25600 | s4@49152 16384   (ping-pong, no overlaps)
// ---------------------------------------------------------------------------
extern "C" __global__ void __launch_bounds__(256, 2)
gnn_paf_mfma(const float* __restrict__ cnn, const unsigned short* __restrict__ wB,
             const float* __restrict__ b0, const float* __restrict__ b1,
             const float* __restrict__ b2, const float* __restrict__ b3,
             const float* __restrict__ b4, const float* __restrict__ b5,
             const float* __restrict__ w6, const float* __restrict__ b6,
             float* __restrict__ out)
{
    __shared__ __align__(64) unsigned char smem[65536];
    unsigned short* s_in = (unsigned short*)(smem);
    unsigned char*  s0   = smem + 32768;
    unsigned char*  s1   = smem;
    unsigned char*  s2   = smem + 28672;
    unsigned char*  s3   = smem;
    unsigned char*  s4   = smem + 49152;

    const int tid  = threadIdx.x;
    const int lane = tid & 63, wave = tid >> 6;       // 4 waves
    const int tile = blockIdx.x, img = blockIdx.y;
    const int oy = (tile >> 3) * 16, ox = (tile & 7) * 16;
    const int n = img / 19, g = img - n * 19;
    const int ch0 = EDGE_A[g], ch1 = EDGE_B[g], ch2 = 19 + 2 * g, ch3 = 20 + 2 * g;
    const int nl = lane & 15, quad = lane >> 4;

    // ---- gather -> s_in bf16 HWC4 (36x36 halo, zero-padded)
    {
        const long long nb = (long long)n * 57 * 16384;
        for (int p = tid; p < 1296; p += 256) {
            int r = p / 36, col = p - r * 36;
            int gy = oy - 10 + r, gx = ox - 10 + col;
            ushort4 v = {0, 0, 0, 0};
            if ((unsigned)gy < 128u && (unsigned)gx < 128u) {
                int off = gy * 128 + gx;
                v.x = f2bf(cnn[nb + (long long)ch0 * 16384 + off]);
                v.y = f2bf(cnn[nb + (long long)ch1 * 16384 + off]);
                v.z = f2bf(cnn[nb + (long long)ch2 * 16384 + off]);
                v.w = f2bf(cnn[nb + (long long)ch3 * 16384 + off]);
            }
            *(ushort4*)(s_in + p * 4) = v;
        }
    }
    __syncthreads();

    // ---- conv0 (4->16) 16x16x32 MFMA: K=32 = 8 taps x 4 ch, 4 chunks
    {
        bf16x8 wf[4];
#pragma unroll
        for (int c = 0; c < 4; ++c)
            wf[c] = *(const bf16x8*)(wB + 75264 + c * 512 + nl * 32 + quad * 8);
        float4 bb = *(const float4*)(b0 + quad * 4);
#pragma unroll 1
        for (int i = 0; i < 16; ++i) {
            int mt = wave + 4 * i;                 // 64 mtiles
            int p = mt * 16 + nl;
            int y = p >> 5, x = p & 31;
            f32x4 acc = (f32x4)0.f;
#pragma unroll
            for (int c = 0; c < 4; ++c) {
                int t0 = c * 8 + quad * 2, t1 = t0 + 1;
                if (t0 > 24) t0 = 24;
                if (t1 > 24) t1 = 24;              // padded taps; weights zero
                int dy0 = t0 / 5, dx0 = t0 - 5 * dy0;
                int dy1 = t1 / 5, dx1 = t1 - 5 * dy1;
                uint2 lo = *(const uint2*)(s_in + ((y + dy0) * 36 + x + dx0) * 4);
                uint2 hi = *(const uint2*)(s_in + ((y + dy1) * 36 + x + dx1) * 4);
                bf16x8 a;
                ((uint2*)&a)[0] = lo;
                ((uint2*)&a)[1] = hi;
                acc = __builtin_amdgcn_mfma_f32_16x16x32_bf16(wf[c], a, acc, 0, 0, 0);
            }
            bool oob = ((unsigned)(oy - 8 + y) >= 128u) || ((unsigned)(ox - 8 + x) >= 128u);
            int lin = p * 32 + quad * 8;
            *(ushort4*)(s0 + sw<16>(lin)) = pack_relu4(acc, bb, oob);
        }
    }
    __syncthreads();

    conv_p16<32, 28, 1, 13, true, 5>(s0, s1, wB + 0,     b1, oy - 6, ox - 6, wave, lane);
    __syncthreads();
    conv_p16<28, 24, 2,  9, false, 5>(s1, s2, wB + 6656,  b2, oy - 4, ox - 4, wave, lane);
    __syncthreads();
    conv_c32f<24, 20, 7, true,  5>(s2, s3, wB + 19968, b3, oy - 2, ox - 2, wave, lane);
    __syncthreads();
    conv_c32f<20, 16, 4, false, 5>(s3, s4, wB + 45568, b4, oy,     ox,     wave, lane);
    __syncthreads();

    // ---- conv5 (1x1 32->128) 16x16x32 + relu + conv6 (128->2)
    {
        bf16x8 w5f[8];
#pragma unroll
        for (int nt = 0; nt < 8; ++nt)
            w5f[nt] = *(const bf16x8*)(wB + 71168 + nt * 512 + nl * 32 + quad * 8);
        const float b6q = b6[quad & 1];
#pragma unroll 1
        for (int ii = 0; ii < 4; ++ii) {
            int mt = wave + 4 * ii;                // 16 mtiles
            int lin = (mt * 16 + nl) * 64 + quad * 16;
            bf16x8 pf = *(const bf16x8*)(s4 + sw<48>(lin));
            float o0 = 0.f, o1 = 0.f;
#pragma unroll
            for (int nt = 0; nt < 8; ++nt) {
                f32x4 acc = (f32x4)0.f;
                acc = __builtin_amdgcn_mfma_f32_16x16x32_bf16(w5f[nt], pf, acc, 0, 0, 0);
                float4 bb  = *(const float4*)(b5 + nt * 16 + quad * 4);
                float4 wa  = *(const float4*)(w6 + nt * 16 + quad * 4);
                float4 wb2 = *(const float4*)(w6 + 128 + nt * 16 + quad * 4);
                float h0 = fmaxf(acc[0] + bb.x, 0.f), h1 = fmaxf(acc[1] + bb.y, 0.f);
                float h2 = fmaxf(acc[2] + bb.z, 0.f), h3 = fmaxf(acc[3] + bb.w, 0.f);
                o0 = fmaf(h0, wa.x, fmaf(h1, wa.y, fmaf(h2, wa.z, fmaf(h3, wa.w, o0))));
                o1 = fmaf(h0, wb2.x, fmaf(h1, wb2.y, fmaf(h2, wb2.z, fmaf(h3, wb2.w, o1))));
            }
            o0 += __shfl_xor(o0, 16, 64); o0 += __shfl_xor(o0, 32, 64);
            o1 += __shfl_xor(o1, 16, 64); o1 += __shfl_xor(o1, 32, 64);
            if (quad < 2) {
                float val = ((quad == 0) ? o0 : o1) + b6q;
                long long ob = (((long long)n * 38 + 2 * g + quad) * 128 + (oy + mt)) * 128 + (ox + nl);
                out[ob] = val;
            }
        }
    }
}

extern "C" void kernel_launch(void* const* d_in, const int* in_sizes, int n_in,
                              void* d_out, int out_size, void* d_ws, size_t ws_size,
                              hipStream_t stream) {
    const float* cnn = (const float*)d_in[0];
    const float* w0 = (const float*)d_in[2];  const float* b0 = (const float*)d_in[3];
    const float* w1 = (const float*)d_in[4];  const float* b1 = (const float*)d_in[5];
    const float* w2 = (const float*)d_in[6];  const float* b2 = (const float*)d_in[7];
    const float* w3 = (const float*)d_in[8];  const float* b3 = (const float*)d_in[9];
    const float* w4 = (const float*)d_in[10]; const float* b4 = (const float*)d_in[11];
    const float* w5 = (const float*)d_in[12]; const float* b5 = (const float*)d_in[13];
    const float* w6 = (const float*)d_in[14]; const float* b6 = (const float*)d_in[15];
    float* out = (float*)d_out;
    unsigned short* wB = (unsigned short*)d_ws;   // 154,624 B used

    hipLaunchKernelGGL(reorder_weights, dim3(302), dim3(256), 0, stream,
                       w0, w1, w2, w3, w4, w5, wB);
    hipLaunchKernelGGL(gnn_paf_mfma, dim3(64, 304), dim3(256), 0, stream,
                       cnn, wB, b0, b1, b2, b3, b4, b5, w6, b6, out);
}

// Round 9
// 1575.341 us; speedup vs baseline: 1.7222x; 1.1861x over previous
//
#include <hip/hip_runtime.h>
#include <hip/hip_bf16.h>

typedef __bf16  bf16x8 __attribute__((ext_vector_type(8)));
typedef float   f32x4  __attribute__((ext_vector_type(4)));

__device__ __constant__ int EDGE_A[19] = {1,8,9,1,11,12,1,2,3,2,1,5,6,5,0,0,0,14,15};
__device__ __constant__ int EDGE_B[19] = {8,9,10,11,12,13,2,3,4,16,5,6,7,17,1,14,15,16,17};

__device__ __forceinline__ unsigned short f2bf(float f) {
    unsigned int x = __float_as_uint(f);
    x += 0x7FFFu + ((x >> 16) & 1u);
    return (unsigned short)(x >> 16);
}

// packed fp32x2 -> bf16x2 (v_cvt_pk_bf16_f32 on gfx950), RNE
__device__ __forceinline__ unsigned int pack2(float a, float b) {
    __hip_bfloat162 t = __float22bfloat162_rn(make_float2(a, b));
    unsigned int r; __builtin_memcpy(&r, &t, 4); return r;
}

// XOR-swizzle on LDS byte offsets (16B-granule-preserving).
template<int MASK>
__device__ __forceinline__ int sw(int lin) { return lin ^ ((lin >> 3) & MASK); }

__device__ __forceinline__ void store_relu4(unsigned char* dst, f32x4 a, float4 b, bool oob) {
    unsigned int lo = pack2(fmaxf(a[0] + b.x, 0.f), fmaxf(a[1] + b.y, 0.f));
    unsigned int hi = pack2(fmaxf(a[2] + b.z, 0.f), fmaxf(a[3] + b.w, 0.f));
    uint2 v; v.x = oob ? 0u : lo; v.y = oob ? 0u : hi;
    *(uint2*)dst = v;
}

// ---------------------------------------------------------------------------
// Weight pre-pass (elem offsets in ws):
//   W1  @0     : 13tp x 16n x 32k              6656  (k=h*16+ic, t=2tp+h)
//   W2  @6656  : 13tp x 2nt x 16 x 32         13312  (same pairing)
//   W3P @19968 : 2h x 13tp x 2nt x 16 x 32    26624  (k=ht*16+icl, ic=h*16+icl)
//   W4  @46592 : 25tap x 2ih x 16 x 32        25600  (k=ic half)
//   W5  @72192 : 8nt x 16 x 32                 4096
//   W0  @76288 : 4c x 16 x 32                  2048  (k=tl*4+ic, t=c*8+tl)
// total 78336 elems = 156672 B
// ---------------------------------------------------------------------------
extern "C" __global__ void __launch_bounds__(256)
reorder_weights(const float* __restrict__ w0, const float* __restrict__ w1,
                const float* __restrict__ w2, const float* __restrict__ w3,
                const float* __restrict__ w4, const float* __restrict__ w5,
                unsigned short* __restrict__ ws)
{
    int idx = blockIdx.x * 256 + threadIdx.x;
    if (idx < 6656) {
        int k = idx & 31, n = (idx >> 5) & 15, tp = idx >> 9;
        int t = 2 * tp + (k >> 4), ic = k & 15;
        float v = (t < 25) ? w1[(n * 16 + ic) * 25 + t] : 0.f;
        ws[idx] = f2bf(v);
    } else if (idx < 19968) {
        int j = idx - 6656;
        int k = j & 31, n = (j >> 5) & 15, nt = (j >> 9) & 1, tp = j >> 10;
        int t = 2 * tp + (k >> 4), ic = k & 15, oc = nt * 16 + n;
        float v = (t < 25) ? w2[(oc * 16 + ic) * 25 + t] : 0.f;
        ws[idx] = f2bf(v);
    } else if (idx < 46592) {
        int j = idx - 19968;
        int k = j & 31, n = (j >> 5) & 15, nt = (j >> 9) & 1, q = j >> 10;
        int h = q / 13, tp = q - 13 * h;
        int t = 2 * tp + (k >> 4), icl = k & 15;
        float v = (t < 25) ? w3[((nt * 16 + n) * 32 + h * 16 + icl) * 25 + t] : 0.f;
        ws[idx] = f2bf(v);
    } else if (idx < 72192) {
        int j = idx - 46592;
        int k = j & 31, n = (j >> 5) & 15, nt = (j >> 9) & 1, tap = j >> 10;
        ws[idx] = f2bf(w4[((nt * 16 + n) * 32 + k) * 25 + tap]);
    } else if (idx < 76288) {
        int j = idx - 72192;
        int k = j & 31, oc = j >> 5;
        ws[idx] = f2bf(w5[oc * 32 + k]);
    } else if (idx < 78336) {
        int j = idx - 76288;
        int k = j & 31, n = (j >> 5) & 15, c = j >> 9;
        int t = c * 8 + (k >> 2), ic = k & 3;
        float v = (t < 25) ? w0[(n * 4 + ic) * 25 + t] : 0.f;
        ws[idx] = f2bf(v);
    }
}

// ---------------------------------------------------------------------------
// Paired-tap 5x5 stage (CIN=16), 16x16x32, generalized for row-slabs (POFF =
// output pixel offset, multiple of SOUT) and accumulate-across-calls
// (ACCIN/EPI) for the conv3 ic-half split. NTW = weight planes per tap.
// ---------------------------------------------------------------------------
template<int SIN, int SOUT, int NPXL, int NT, int NTW, int MAXM, int CH, bool ACCIN, bool EPI>
__device__ __forceinline__ void conv_pair16(
    const unsigned char* __restrict__ sinB, unsigned char* __restrict__ soutB,
    const unsigned short* __restrict__ wA, const float* __restrict__ bias,
    f32x4 (&acc)[MAXM][NT], int POFF, int gy0, int gx0, int wave, int lane, int ntSel)
{
    constexpr int NM = (NPXL + 15) / 16;
    constexpr int OMASK = (NT == 1) ? 16 : 48;
    const int nl = lane & 15, quad = lane >> 4;
    const int h = quad >> 1;
    const int coff = (quad & 1) * 16;

    int abase[MAXM];
#pragma unroll
    for (int i = 0; i < MAXM; ++i) {
        int p = (wave + 4 * i) * 16 + nl;
        if (p > NPXL - 1) p = NPXL - 1;        // clamp partial mtile
        int y = p / SOUT, x = p - y * SOUT;
        abase[i] = (y * SIN + x) * 32 + coff;
    }
    if (!ACCIN) {
#pragma unroll
        for (int i = 0; i < MAXM; ++i)
#pragma unroll
            for (int nt = 0; nt < NT; ++nt) acc[i][nt] = (f32x4)0.f;
    }
    const unsigned short* wp = wA + ntSel * 512 + nl * 32 + quad * 8;

#pragma unroll 1
    for (int c0 = 0; c0 < 13; c0 += CH) {
        bf16x8 wf[CH][NT];
#pragma unroll
        for (int tp = 0; tp < CH; ++tp)
            if (c0 + tp < 13)
#pragma unroll
                for (int nt = 0; nt < NT; ++nt)
                    wf[tp][nt] = *(const bf16x8*)(wp + ((c0 + tp) * NTW + nt) * 512);
#pragma unroll
        for (int tp = 0; tp < CH; ++tp) {
            if (c0 + tp < 13) {
                int t = 2 * (c0 + tp) + h;
                if (t > 24) t = 24;            // padded half; weights zero
                int dy = t / 5, dx = t - 5 * dy;
                int toff = (dy * SIN + dx) * 32;
#pragma unroll
                for (int i = 0; i < MAXM; ++i)
                    if (wave + 4 * i < NM) {
                        bf16x8 a = *(const bf16x8*)(sinB + sw<16>(abase[i] + toff));
#pragma unroll
                        for (int nt = 0; nt < NT; ++nt)
                            acc[i][nt] = __builtin_amdgcn_mfma_f32_16x16x32_bf16(wf[tp][nt], a, acc[i][nt], 0, 0, 0);
                    }
            }
        }
    }

    if (EPI) {
#pragma unroll
        for (int i = 0; i < MAXM; ++i) {
            int p = (wave + 4 * i) * 16 + nl;
            if (p < NPXL) {
                int pg = p + POFF;
                int y = pg / SOUT, x = pg - y * SOUT;
                bool oob = ((unsigned)(gy0 + y) >= 128u) || ((unsigned)(gx0 + x) >= 128u);
#pragma unroll
                for (int nt = 0; nt < NT; ++nt) {
                    float4 bb = *(const float4*)(bias + nt * 16 + quad * 4);
                    int lin = pg * (NT * 32) + nt * 32 + quad * 8;
                    store_relu4(soutB + sw<OMASK>(lin), acc[i][nt], bb, oob);
                }
            }
        }
    }
}

// ---------------------------------------------------------------------------
// CIN=32 5x5 stage (K=32 ic), nt-fused (conv4: 20->16, NM=16 exact).
// ---------------------------------------------------------------------------
template<int SIN, int SOUT, int MAXM, int CH>
__device__ __forceinline__ void conv_c32(
    const unsigned char* __restrict__ sinB, unsigned char* __restrict__ soutB,
    const unsigned short* __restrict__ wA, const float* __restrict__ bias,
    int gy0, int gx0, int wave, int lane)
{
    const int nl = lane & 15, quad = lane >> 4;
    int abase[MAXM];
#pragma unroll
    for (int i = 0; i < MAXM; ++i) {
        int p = (wave + 4 * i) * 16 + nl;
        int y = p / SOUT, x = p - y * SOUT;
        abase[i] = (y * SIN + x) * 64 + quad * 16;
    }
    f32x4 acc[MAXM][2];
#pragma unroll
    for (int i = 0; i < MAXM; ++i) { acc[i][0] = (f32x4)0.f; acc[i][1] = (f32x4)0.f; }

    const unsigned short* wp = wA + nl * 32 + quad * 8;

#pragma unroll 1
    for (int c0 = 0; c0 < 25; c0 += CH) {
        bf16x8 wf[CH][2];
#pragma unroll
        for (int tp = 0; tp < CH; ++tp)
            if (c0 + tp < 25) {
                wf[tp][0] = *(const bf16x8*)(wp + ((c0 + tp) * 2 + 0) * 512);
                wf[tp][1] = *(const bf16x8*)(wp + ((c0 + tp) * 2 + 1) * 512);
            }
#pragma unroll
        for (int tp = 0; tp < CH; ++tp) {
            if (c0 + tp < 25) {
                int t = c0 + tp;
                int dy = t / 5, dx = t - 5 * dy;
                int toff = (dy * SIN + dx) * 64;
#pragma unroll
                for (int i = 0; i < MAXM; ++i) {
                    bf16x8 a = *(const bf16x8*)(sinB + sw<48>(abase[i] + toff));
                    acc[i][0] = __builtin_amdgcn_mfma_f32_16x16x32_bf16(wf[tp][0], a, acc[i][0], 0, 0, 0);
                    acc[i][1] = __builtin_amdgcn_mfma_f32_16x16x32_bf16(wf[tp][1], a, acc[i][1], 0, 0, 0);
                }
            }
        }
    }

#pragma unroll
    for (int i = 0; i < MAXM; ++i) {
        int p = (wave + 4 * i) * 16 + nl;
        int y = p / SOUT, x = p - y * SOUT;
        bool oob = ((unsigned)(gy0 + y) >= 128u) || ((unsigned)(gx0 + x) >= 128u);
#pragma unroll
        for (int nt = 0; nt < 2; ++nt) {
            float4 bb = *(const float4*)(bias + nt * 16 + quad * 4);
            int lin = p * 64 + nt * 32 + quad * 8;
            store_relu4(soutB + sw<48>(lin), acc[i][nt], bb, oob);
        }
    }
}

// ---------------------------------------------------------------------------
// conv0 (4->16) on an 18-row slab: 36 mtiles, K=32 = 8 taps x 4ch.
// Slab storage is row-offset-free (local rows); yoff only affects oob mask.
// ---------------------------------------------------------------------------
__device__ __forceinline__ void conv0_slab(
    const unsigned short* __restrict__ s_in, unsigned char* __restrict__ s0,
    const unsigned short* __restrict__ wB, const float* __restrict__ b0,
    int yoff, int oy, int ox, int wave, int lane)
{
    const int nl = lane & 15, quad = lane >> 4;
    bf16x8 wf[4];
#pragma unroll
    for (int c = 0; c < 4; ++c)
        wf[c] = *(const bf16x8*)(wB + 76288 + c * 512 + nl * 32 + quad * 8);
    float4 bb = *(const float4*)(b0 + quad * 4);
#pragma unroll 1
    for (int i = 0; i < 9; ++i) {
        int mt = wave + 4 * i;                 // 36 mtiles = 576 px (18 rows x 32)
        int p = mt * 16 + nl;
        int y = p >> 5, x = p & 31;
        f32x4 acc = (f32x4)0.f;
#pragma unroll
        for (int c = 0; c < 4; ++c) {
            int t0 = c * 8 + quad * 2, t1 = t0 + 1;
            if (t0 > 24) t0 = 24;
            if (t1 > 24) t1 = 24;              // padded taps; weights zero
            int dy0 = t0 / 5, dx0 = t0 - 5 * dy0;
            int dy1 = t1 / 5, dx1 = t1 - 5 * dy1;
            uint2 lo = *(const uint2*)(s_in + ((y + dy0) * 36 + x + dx0) * 4);
            uint2 hi = *(const uint2*)(s_in + ((y + dy1) * 36 + x + dx1) * 4);
            bf16x8 a;
            ((uint2*)&a)[0] = lo; ((uint2*)&a)[1] = hi;
            acc = __builtin_amdgcn_mfma_f32_16x16x32_bf16(wf[c], a, acc, 0, 0, 0);
        }
        bool oob = ((unsigned)(oy - 8 + y + yoff) >= 128u) || ((unsigned)(ox - 8 + x) >= 128u);
        int lin = p * 32 + quad * 8;
        store_relu4(s0 + sw<16>(lin), acc, bb, oob);
    }
}

// ---------------------------------------------------------------------------
// Fused pipeline, 3 blocks/CU: one 256-thread block = one 16x16 output tile.
// LDS map (50368 B total):
//   s1  @0      25088  [conv1a..conv2b]      s3 @0 25600 [conv3b..conv4]
//   s_in@25600   6336  [gather..conv0b]      s2h/s4 @25600 (18432/16384)
//   s0  @31936  18432  [conv0a..conv1b]
// Schedule: gatherA|c0a|gatherB+c1a|c0b|c1b|c2a|c3a|c2b|c3b|c4|c5
// ---------------------------------------------------------------------------
extern "C" __global__ void __launch_bounds__(256, 3)
gnn_paf_mfma(const float* __restrict__ cnn, const unsigned short* __restrict__ wB,
             const float* __restrict__ b0, const float* __restrict__ b1,
             const float* __restrict__ b2, const float* __restrict__ b3,
             const float* __restrict__ b4, const float* __restrict__ b5,
             const float* __restrict__ w6, const float* __restrict__ b6,
             float* __restrict__ out)
{
    __shared__ __align__(64) unsigned char smem[50368];
    unsigned char*  const s1  = smem;                              // 25088
    unsigned char*  const s3  = smem;                              // 25600
    unsigned short* const sin_ = (unsigned short*)(smem + 25600);  // 6336
    unsigned char*  const s2h = smem + 25600;                      // 18432
    unsigned char*  const s4  = smem + 25600;                      // 16384
    unsigned char*  const s0  = smem + 31936;                      // 18432

    const int tid  = threadIdx.x;
    const int lane = tid & 63, wave = tid >> 6;       // 4 waves
    const int tile = blockIdx.x, img = blockIdx.y;
    const int oy = (tile >> 3) * 16, ox = (tile & 7) * 16;
    const int n = img / 19, g = img - n * 19;
    const int ch0 = EDGE_A[g], ch1 = EDGE_B[g], ch2 = 19 + 2 * g, ch3 = 20 + 2 * g;
    const int nl = lane & 15, quad = lane >> 4;
    const long long nb = (long long)n * 57 * 16384;

    // ---- gatherA: halo rows 0..21 -> sin_ (22x36x4 bf16, zero-padded)
    for (int idx = tid; idx < 792; idx += 256) {
        int r = idx / 36, c = idx - r * 36;
        int gy = oy - 10 + r, gx = ox - 10 + c;
        float v0 = 0.f, v1 = 0.f, v2 = 0.f, v3 = 0.f;
        if ((unsigned)gy < 128u && (unsigned)gx < 128u) {
            int off = gy * 128 + gx;
            v0 = cnn[nb + (long long)ch0 * 16384 + off];
            v1 = cnn[nb + (long long)ch1 * 16384 + off];
            v2 = cnn[nb + (long long)ch2 * 16384 + off];
            v3 = cnn[nb + (long long)ch3 * 16384 + off];
        }
        uint2 v; v.x = pack2(v0, v1); v.y = pack2(v2, v3);
        *(uint2*)(sin_ + idx * 4) = v;
    }
    __syncthreads();

    conv0_slab(sin_, s0, wB, b0, 0, oy, ox, wave, lane);       // s0 rows 0..17
    __syncthreads();

    // ---- gatherB loads (rows 14..35) pipelined across conv1a
    float gv[4][4];
#pragma unroll
    for (int j = 0; j < 4; ++j) {
        gv[j][0] = gv[j][1] = gv[j][2] = gv[j][3] = 0.f;
        int idx = tid + 256 * j;
        if (idx < 792) {
            int r = idx / 36, c = idx - r * 36;
            int gy = oy + 4 + r, gx = ox - 10 + c;                 // -10+14+r
            if ((unsigned)gy < 128u && (unsigned)gx < 128u) {
                int off = gy * 128 + gx;
                gv[j][0] = cnn[nb + (long long)ch0 * 16384 + off];
                gv[j][1] = cnn[nb + (long long)ch1 * 16384 + off];
                gv[j][2] = cnn[nb + (long long)ch2 * 16384 + off];
                gv[j][3] = cnn[nb + (long long)ch3 * 16384 + off];
            }
        }
    }
    {   // conv1a: s1 rows 0..13 (px 0..391) from s0 slab A
        f32x4 a1[7][1];
        conv_pair16<32, 28, 392, 1, 1, 7, 5, false, true>(s0, s1, wB, b1, a1,
                                                          0, oy - 6, ox - 6, wave, lane, 0);
    }
#pragma unroll
    for (int j = 0; j < 4; ++j) {
        int idx = tid + 256 * j;
        if (idx < 792) {
            uint2 v; v.x = pack2(gv[j][0], gv[j][1]); v.y = pack2(gv[j][2], gv[j][3]);
            *(uint2*)(sin_ + idx * 4) = v;
        }
    }
    __syncthreads();

    conv0_slab(sin_, s0, wB, b0, 14, oy, ox, wave, lane);      // s0 rows 14..31
    __syncthreads();

    {   // conv1b: s1 rows 14..27 (px 392..783)
        f32x4 a1[7][1];
        conv_pair16<32, 28, 392, 1, 1, 7, 5, false, true>(s0, s1, wB, b1, a1,
                                                          392, oy - 6, ox - 6, wave, lane, 0);
    }
    __syncthreads();

    {   // conv2a: oc 0..15 -> s2h
        f32x4 a2[9][1];
        conv_pair16<28, 24, 576, 1, 2, 9, 3, false, true>(s1, s2h, wB + 6656, b2, a2,
                                                          0, oy - 4, ox - 4, wave, lane, 0);
    }
    __syncthreads();

    f32x4 acc3[7][2];
    // conv3a: accumulate ic-half 0 (acc3 held across conv2b)
    conv_pair16<24, 20, 400, 2, 2, 7, 3, false, false>(s2h, s3, wB + 19968, b3, acc3,
                                                       0, oy - 2, ox - 2, wave, lane, 0);
    __syncthreads();

    {   // conv2b: oc 16..31 -> s2h (overwrite)
        f32x4 a2[9][1];
        conv_pair16<28, 24, 576, 1, 2, 9, 3, false, true>(s1, s2h, wB + 6656, b2 + 16, a2,
                                                          0, oy - 4, ox - 4, wave, lane, 1);
    }
    __syncthreads();

    // conv3b: accumulate ic-half 1, epilogue -> s3
    conv_pair16<24, 20, 400, 2, 2, 7, 3, true, true>(s2h, s3, wB + 19968 + 13312, b3, acc3,
                                                     0, oy - 2, ox - 2, wave, lane, 0);
    __syncthreads();

    conv_c32<20, 16, 4, 5>(s3, s4, wB + 46592, b4, oy, ox, wave, lane);
    __syncthreads();

    // ---- conv5 (1x1 32->128) + relu + conv6 (128->2)
    {
        bf16x8 w5f[8];
#pragma unroll
        for (int nt = 0; nt < 8; ++nt)
            w5f[nt] = *(const bf16x8*)(wB + 72192 + nt * 512 + nl * 32 + quad * 8);
        const float b6q = b6[quad & 1];
#pragma unroll 1
        for (int ii = 0; ii < 4; ++ii) {
            int mt = wave + 4 * ii;                // 16 mtiles
            int lin = (mt * 16 + nl) * 64 + quad * 16;
            bf16x8 pf = *(const bf16x8*)(s4 + sw<48>(lin));
            float o0 = 0.f, o1 = 0.f;
#pragma unroll
            for (int nt = 0; nt < 8; ++nt) {
                f32x4 acc = (f32x4)0.f;
                acc = __builtin_amdgcn_mfma_f32_16x16x32_bf16(w5f[nt], pf, acc, 0, 0, 0);
                float4 bb  = *(const float4*)(b5 + nt * 16 + quad * 4);
                float4 wa  = *(const float4*)(w6 + nt * 16 + quad * 4);
                float4 wb2 = *(const float4*)(w6 + 128 + nt * 16 + quad * 4);
                float h0 = fmaxf(acc[0] + bb.x, 0.f), h1 = fmaxf(acc[1] + bb.y, 0.f);
                float h2 = fmaxf(acc[2] + bb.z, 0.f), h3 = fmaxf(acc[3] + bb.w, 0.f);
                o0 = fmaf(h0, wa.x, fmaf(h1, wa.y, fmaf(h2, wa.z, fmaf(h3, wa.w, o0))));
                o1 = fmaf(h0, wb2.x, fmaf(h1, wb2.y, fmaf(h2, wb2.z, fmaf(h3, wb2.w, o1))));
            }
            o0 += __shfl_xor(o0, 16, 64); o0 += __shfl_xor(o0, 32, 64);
            o1 += __shfl_xor(o1, 16, 64); o1 += __shfl_xor(o1, 32, 64);
            if (quad < 2) {
                float val = ((quad == 0) ? o0 : o1) + b6q;
                long long ob = (((long long)n * 38 + 2 * g + quad) * 128 + (oy + mt)) * 128 + (ox + nl);
                out[ob] = val;
            }
        }
    }
}

extern "C" void kernel_launch(void* const* d_in, const int* in_sizes, int n_in,
                              void* d_out, int out_size, void* d_ws, size_t ws_size,
                              hipStream_t stream) {
    const float* cnn = (const float*)d_in[0];
    const float* w0 = (const float*)d_in[2];  const float* b0 = (const float*)d_in[3];
    const float* w1 = (const float*)d_in[4];  const float* b1 = (const float*)d_in[5];
    const float* w2 = (const float*)d_in[6];  const float* b2 = (const float*)d_in[7];
    const float* w3 = (const float*)d_in[8];  const float* b3 = (const float*)d_in[9];
    const float* w4 = (const float*)d_in[10]; const float* b4 = (const float*)d_in[11];
    const float* w5 = (const float*)d_in[12]; const float* b5 = (const float*)d_in[13];
    const float* w6 = (const float*)d_in[14]; const float* b6 = (const float*)d_in[15];
    float* out = (float*)d_out;
    unsigned short* wB = (unsigned short*)d_ws;   // 156,672 B used

    hipLaunchKernelGGL(reorder_weights, dim3(306), dim3(256), 0, stream,
                       w0, w1, w2, w3, w4, w5, wB);
    hipLaunchKernelGGL(gnn_paf_mfma, dim3(64, 304), dim3(256), 0, stream,
                       cnn, wB, b0, b1, b2, b3, b4, b5, w6, b6, out);
}